// Round 5
// baseline (336.428 us; speedup 1.0000x reference)
//
#include <hip/hip_runtime.h>
#include <math.h>

#define LOG2PI_F 1.8378770664093453f
#define BN_EPS 1e-5f
#define NB1 2048         // blocks for K1 (16 rows each)
#define RPB1 16
#define NB3 1024         // blocks for K3 (32 rows each)
#define RPB3 32
#define BATCH 32768

// ---------------- K1: x@W1.T + b1, ReLU, SPN layer 1 ----------------
// block 256 threads = 16 rows x 16 k-slices; grid 2048
__global__ __launch_bounds__(256, 4) void k1_gemm_spn1(
    const float* __restrict__ x, const float* __restrict__ W1, const float* __restrict__ b1,
    const float* __restrict__ mean1, const float* __restrict__ std1, const float* __restrict__ sw1,
    const int* __restrict__ scopes1,
    float* __restrict__ s1, float* __restrict__ partials1)
{
    __shared__ float h_lds[16 * 33];
    __shared__ float mu_l[1024], inv_l[1024], c0_l[512];
    __shared__ int   sc_l[512];
    __shared__ float b1_l[32];
    __shared__ float sv_l[16 * 17];

    const int t = threadIdx.x;

    // ---- per-block SPN1 constants, stored o-last for broadcast reads ----
    for (int il = t; il < 1024; il += 256) {
        int o = il & 15, rest = il >> 4;
        int f = rest & 1, m = (rest >> 1) & 1, p = rest >> 2;
        int ig = ((o * 16 + p) * 2 + m) * 2 + f;
        mu_l[il]  = mean1[ig];
        inv_l[il] = 1.0f / std1[ig];
    }
    for (int il = t; il < 512; il += 256) {
        int o = il & 15, rest = il >> 4;
        int m = rest & 1, p = rest >> 1;
        int igw = (o * 16 + p) * 2;
        float w0 = sw1[igw], w1 = sw1[igw + 1];
        float mx = fmaxf(w0, w1);
        float lse = mx + __logf(__expf(w0 - mx) + __expf(w1 - mx));
        float wm = (m == 0) ? w0 : w1;
        int igs = ((o * 16 + p) * 2 + m) * 2;
        c0_l[il] = (wm - lse) - __logf(std1[igs]) - __logf(std1[igs + 1]) - LOG2PI_F;
    }
    for (int il = t; il < 512; il += 256) sc_l[il] = scopes1[il];
    if (t < 32) b1_l[t] = b1[t];

    // ---- GEMM: 16 rows/block, 16 lanes per row split K=784 ----
    const int r = t >> 4, j = t & 15;
    const int row = blockIdx.x * RPB1 + r;
    const float* xr = x + (size_t)row * 784;

    float acc[32];
    #pragma unroll
    for (int o = 0; o < 32; ++o) acc[o] = 0.f;

    #pragma unroll 1
    for (int c = 0; c < 13; ++c) {
        int k0 = c * 64 + j * 4;
        bool valid = (k0 < 784);
        int k = valid ? k0 : 0;
        float4 xv;
        if (valid) xv = *(const float4*)(xr + k);
        else { xv.x = 0.f; xv.y = 0.f; xv.z = 0.f; xv.w = 0.f; }
        const float* wp = W1 + k;
        // 4 groups of 8 outputs: 8 independent loads in flight per group
        #pragma unroll
        for (int g = 0; g < 4; ++g) {
            float4 w[8];
            #pragma unroll
            for (int i = 0; i < 8; ++i)
                w[i] = *(const float4*)(wp + (g * 8 + i) * 784);
            #pragma unroll
            for (int i = 0; i < 8; ++i) {
                int o = g * 8 + i;
                acc[o] = fmaf(xv.x, w[i].x, acc[o]);
                acc[o] = fmaf(xv.y, w[i].y, acc[o]);
                acc[o] = fmaf(xv.z, w[i].z, acc[o]);
                acc[o] = fmaf(xv.w, w[i].w, acc[o]);
            }
        }
    }

    // butterfly reduce over the 16 k-slices
    #pragma unroll
    for (int o = 0; o < 32; ++o) {
        float v = acc[o];
        v += __shfl_xor(v, 1);
        v += __shfl_xor(v, 2);
        v += __shfl_xor(v, 4);
        v += __shfl_xor(v, 8);
        acc[o] = v;
    }
    {
        int o0 = 2 * j, o1 = 2 * j + 1;
        h_lds[r * 33 + o0] = fmaxf(acc[o0] + b1_l[o0], 0.f);
        h_lds[r * 33 + o1] = fmaxf(acc[o1] + b1_l[o1], 0.f);
    }
    __syncthreads();

    // ---- SPN1: 256 (row, o) tasks, one per thread ----
    {
        int row_l = t >> 4, o = t & 15;
        float outv = 0.f;
        for (int p = 0; p < 16; ++p) {
            int f0 = sc_l[o * 32 + 2 * p], f1 = sc_l[o * 32 + 2 * p + 1];
            float x0 = h_lds[row_l * 33 + f0];
            float x1 = h_lds[row_l * 33 + f1];
            float vm[2];
            #pragma unroll
            for (int m = 0; m < 2; ++m) {
                int base = ((p * 2 + m) * 2) * 16 + o;
                float d0 = (x0 - mu_l[base])      * inv_l[base];
                float d1 = (x1 - mu_l[base + 16]) * inv_l[base + 16];
                vm[m] = c0_l[(p * 2 + m) * 16 + o] - 0.5f * (d0 * d0 + d1 * d1);
            }
            float a  = fmaxf(vm[0], vm[1]);
            float bm = fminf(vm[0], vm[1]);
            outv += a + __logf(1.f + __expf(bm - a));
        }
        s1[(size_t)(blockIdx.x * RPB1 + row_l) * 16 + o] = outv;
        sv_l[o * 17 + row_l] = outv;
    }
    __syncthreads();

    // ---- per-block centered stats (sum, M2) per output column ----
    if (t < 16) {
        float s = 0.f;
        for (int rr = 0; rr < RPB1; ++rr) s += sv_l[t * 17 + rr];
        float mb = s * (1.f / RPB1);
        float m2 = 0.f;
        for (int rr = 0; rr < RPB1; ++rr) { float d = sv_l[t * 17 + rr] - mb; m2 += d * d; }
        partials1[blockIdx.x * 32 + t]      = s;
        partials1[blockIdx.x * 32 + 16 + t] = m2;
    }
}

// ---------------- K2/K4: merge per-block stats -> {g, shift} ----------------
template <int NO, int NBLK, int RPB>
__global__ __launch_bounds__(256) void kreduce(
    const float* __restrict__ partials,
    const float* __restrict__ bn_w, const float* __restrict__ bn_b,
    float* __restrict__ stats)
{
    __shared__ double dsum[256];
    __shared__ double dmean[16];
    const int t = threadIdx.x;
    const int o = t & 15, seg = t >> 4;          // 16 segments
    const int per = NBLK / 16;

    double s = 0.0;
    if (o < NO)
        for (int b = seg * per; b < (seg + 1) * per; ++b)
            s += (double)partials[b * (2 * NO) + o];
    dsum[t] = s;
    __syncthreads();
    if (t < 16) {
        double S = 0.0;
        for (int g = 0; g < 16; ++g) S += dsum[g * 16 + t];
        dmean[t] = S / (double)BATCH;
    }
    __syncthreads();
    double mean = dmean[o];
    double m2 = 0.0;
    if (o < NO) {
        for (int b = seg * per; b < (seg + 1) * per; ++b) {
            double bm = (double)partials[b * (2 * NO) + o] / (double)RPB;
            double d  = bm - mean;
            m2 += (double)partials[b * (2 * NO) + NO + o] + (double)RPB * d * d;
        }
    }
    __syncthreads();
    dsum[t] = m2;
    __syncthreads();
    if (t < NO) {
        double M2 = 0.0;
        for (int g = 0; g < 16; ++g) M2 += dsum[g * 16 + t];
        double var = M2 / (double)BATCH;
        double gsc = (double)bn_w[t] / sqrt(var + (double)BN_EPS);
        stats[t]      = (float)gsc;
        stats[NO + t] = (float)((double)bn_b[t] - dmean[t] * gsc);
    }
}

// ---------------- K3: BN1 + SPN layer 2 ----------------
// block 320 threads = 32 rows x 10 outputs; grid 1024
__global__ __launch_bounds__(320, 4) void k3_spn2(
    const float* __restrict__ s1,
    const float* __restrict__ mean2, const float* __restrict__ std2, const float* __restrict__ sw2,
    const int* __restrict__ scopes2, const float* __restrict__ stats1,
    float* __restrict__ s2, float* __restrict__ partials2)
{
    __shared__ float mu_l[320], inv_l[320], c0_l[160];
    __shared__ int   sc_l[160];
    __shared__ float sv_l[10 * 33];
    __shared__ float g_l[16], sh_l[16];

    const int t = threadIdx.x;

    if (t < 320) {   // o-last: il = ((p*2+m)*2+f)*10 + o
        int o = t % 10, rest = t / 10;
        int f = rest & 1, m = (rest >> 1) & 1, p = rest >> 2;
        int ig = ((o * 8 + p) * 2 + m) * 2 + f;
        mu_l[t]  = mean2[ig];
        inv_l[t] = 1.0f / std2[ig];
    }
    if (t < 160) {   // il = (p*2+m)*10 + o
        int o = t % 10, rest = t / 10;
        int m = rest & 1, p = rest >> 1;
        int igw = (o * 8 + p) * 2;
        float w0 = sw2[igw], w1 = sw2[igw + 1];
        float mx = fmaxf(w0, w1);
        float lse = mx + __logf(__expf(w0 - mx) + __expf(w1 - mx));
        float wm = (m == 0) ? w0 : w1;
        int igs = ((o * 8 + p) * 2 + m) * 2;
        c0_l[t] = (wm - lse) - __logf(std2[igs]) - __logf(std2[igs + 1]) - LOG2PI_F;
    }
    if (t < 160) sc_l[t] = scopes2[t];
    if (t < 16)  g_l[t]  = stats1[t];
    else if (t < 32) sh_l[t - 16] = stats1[t];
    __syncthreads();

    const int row_l = t / 10, o = t % 10;
    const int row = blockIdx.x * RPB3 + row_l;
    const float* s1r = s1 + (size_t)row * 16;

    float v[16];
    #pragma unroll
    for (int f = 0; f < 16; ++f) v[f] = fmaf(s1r[f], g_l[f], sh_l[f]);

    float outv = 0.f;
    for (int p = 0; p < 8; ++p) {
        int f0 = sc_l[o * 16 + 2 * p], f1 = sc_l[o * 16 + 2 * p + 1];
        float x0 = v[f0], x1 = v[f1];
        float vm[2];
        #pragma unroll
        for (int m = 0; m < 2; ++m) {
            int base = ((p * 2 + m) * 2) * 10 + o;
            float d0 = (x0 - mu_l[base])      * inv_l[base];
            float d1 = (x1 - mu_l[base + 10]) * inv_l[base + 10];
            vm[m] = c0_l[(p * 2 + m) * 10 + o] - 0.5f * (d0 * d0 + d1 * d1);
        }
        float a  = fmaxf(vm[0], vm[1]);
        float bm = fminf(vm[0], vm[1]);
        outv += a + __logf(1.f + __expf(bm - a));
    }
    s2[(size_t)row * 10 + o] = outv;
    sv_l[o * 33 + row_l] = outv;
    __syncthreads();

    if (t < 10) {
        float s = 0.f;
        for (int rr = 0; rr < RPB3; ++rr) s += sv_l[t * 33 + rr];
        float mb = s * (1.f / RPB3);
        float m2 = 0.f;
        for (int rr = 0; rr < RPB3; ++rr) { float d = sv_l[t * 33 + rr] - mb; m2 += d * d; }
        partials2[blockIdx.x * 20 + t]      = s;
        partials2[blockIdx.x * 20 + 10 + t] = m2;
    }
}

// ---------------- K5: BN2 + final linear + log_softmax ----------------
__global__ __launch_bounds__(256) void k5_head(
    const float* __restrict__ s2, const float* __restrict__ stats2,
    const float* __restrict__ W2, const float* __restrict__ b2,
    float* __restrict__ out)
{
    const int row = blockIdx.x * 256 + threadIdx.x;
    const float* sr = s2 + (size_t)row * 10;
    float v[10], l[10];
    #pragma unroll
    for (int o = 0; o < 10; ++o) v[o] = fmaf(sr[o], stats2[o], stats2[10 + o]);
    float mx = -1e30f;
    #pragma unroll
    for (int c = 0; c < 10; ++c) {
        float a = b2[c];
        #pragma unroll
        for (int o = 0; o < 10; ++o) a = fmaf(W2[c * 10 + o], v[o], a);
        l[c] = a;
        mx = fmaxf(mx, a);
    }
    float sum = 0.f;
    #pragma unroll
    for (int c = 0; c < 10; ++c) sum += __expf(l[c] - mx);
    float ls = mx + __logf(sum);
    float* orow = out + (size_t)row * 10;
    #pragma unroll
    for (int c = 0; c < 10; ++c) orow[c] = l[c] - ls;
}

extern "C" void kernel_launch(void* const* d_in, const int* in_sizes, int n_in,
                              void* d_out, int out_size, void* d_ws, size_t ws_size,
                              hipStream_t stream) {
    const float* x      = (const float*)d_in[0];
    const float* W1     = (const float*)d_in[1];
    const float* b1     = (const float*)d_in[2];
    const float* mean1  = (const float*)d_in[3];
    const float* std1   = (const float*)d_in[4];
    const float* sw1    = (const float*)d_in[5];
    const float* bn1_w  = (const float*)d_in[6];
    const float* bn1_b  = (const float*)d_in[7];
    const float* mean2  = (const float*)d_in[8];
    const float* std2   = (const float*)d_in[9];
    const float* sw2    = (const float*)d_in[10];
    const float* bn2_w  = (const float*)d_in[11];
    const float* bn2_b  = (const float*)d_in[12];
    const float* W2     = (const float*)d_in[13];
    const float* b2     = (const float*)d_in[14];
    const int*   sc1    = (const int*)d_in[15];
    const int*   sc2    = (const int*)d_in[16];
    float* out = (float*)d_out;

    float* ws  = (float*)d_ws;
    float* s1  = ws;                       // 32768*16
    float* s2  = s1 + 32768 * 16;          // 32768*10
    float* p1  = s2 + 32768 * 10;          // 2048*32
    float* p2  = p1 + NB1 * 32;            // 1024*20
    float* st1 = p2 + NB3 * 20;            // 32
    float* st2 = st1 + 32;                 // 20

    hipLaunchKernelGGL(k1_gemm_spn1, dim3(NB1), dim3(256), 0, stream,
                       x, W1, b1, mean1, std1, sw1, sc1, s1, p1);
    hipLaunchKernelGGL((kreduce<16, NB1, RPB1>), dim3(1), dim3(256), 0, stream, p1, bn1_w, bn1_b, st1);
    hipLaunchKernelGGL(k3_spn2, dim3(NB3), dim3(320), 0, stream,
                       s1, mean2, std2, sw2, sc2, st1, s2, p2);
    hipLaunchKernelGGL((kreduce<10, NB3, RPB3>), dim3(1), dim3(256), 0, stream, p2, bn2_w, bn2_b, st2);
    hipLaunchKernelGGL(k5_head, dim3(32768 / 256), dim3(256), 0, stream,
                       s2, st2, W2, b2, out);
}

// Round 6
// 236.391 us; speedup vs baseline: 1.4232x; 1.4232x over previous
//
#include <hip/hip_runtime.h>
#include <hip/hip_bf16.h>
#include <math.h>

#define LOG2PI_F 1.8378770664093453f
#define BN_EPS 1e-5f
#define BATCH 32768

#define K1_ROWS 64
#define NB1 (BATCH / K1_ROWS)    // 512 blocks
#define WS1 840                  // padded K stride for bf16 W1 (>= 832, mult of 8)
#define NB3 1024                 // blocks for K3 (32 rows each)
#define RPB3 32

typedef __attribute__((ext_vector_type(8))) short bf16x8;
typedef __attribute__((ext_vector_type(4))) float f32x4;

// ---------------- K0: W1 fp32 -> bf16 hi/lo (padded, zero-filled) ----------------
__global__ __launch_bounds__(256) void k0_cvt(
    const float* __restrict__ W1, __hip_bfloat16* __restrict__ w1h,
    __hip_bfloat16* __restrict__ w1l)
{
    int i = blockIdx.x * 256 + threadIdx.x;      // over 32*840 = 26880
    if (i >= 32 * WS1) return;
    int o = i / WS1, k = i - o * WS1;
    float w = (k < 784) ? W1[o * 784 + k] : 0.f;
    __hip_bfloat16 h = __float2bfloat16(w);
    float hf = __bfloat162float(h);
    __hip_bfloat16 l = __float2bfloat16(w - hf);
    w1h[i] = h;
    w1l[i] = l;
}

// ---------------- K1: x@W1.T + b1, ReLU, SPN layer 1 (MFMA bf16x3) ----------------
// block 256 threads = 4 waves; 64 rows/block; grid 512
__global__ __launch_bounds__(256, 2) void k1_gemm_spn1(
    const float* __restrict__ x,
    const __hip_bfloat16* __restrict__ w1h, const __hip_bfloat16* __restrict__ w1l,
    const float* __restrict__ b1,
    const float* __restrict__ mean1, const float* __restrict__ std1, const float* __restrict__ sw1,
    const int* __restrict__ scopes1,
    float* __restrict__ s1, float* __restrict__ partials1)
{
    __shared__ __hip_bfloat16 Ah[64][72];   // +8 pad: 144B row stride -> 2-way (free) on frag reads
    __shared__ __hip_bfloat16 Al[64][72];
    __shared__ float h_lds[64][33];
    __shared__ float mu_l[1024], inv_l[1024], c0_l[512];
    __shared__ int   sc_l[512];
    __shared__ float b1_l[32];
    __shared__ float sv_l[16][66];

    const int t = threadIdx.x;

    // ---- SPN1 constant tables, o-last for broadcast reads ----
    for (int il = t; il < 1024; il += 256) {
        int o = il & 15, rest = il >> 4;
        int f = rest & 1, m = (rest >> 1) & 1, p = rest >> 2;
        int ig = ((o * 16 + p) * 2 + m) * 2 + f;
        mu_l[il]  = mean1[ig];
        inv_l[il] = 1.0f / std1[ig];
    }
    for (int il = t; il < 512; il += 256) {
        int o = il & 15, rest = il >> 4;
        int m = rest & 1, p = rest >> 1;
        int igw = (o * 16 + p) * 2;
        float w0 = sw1[igw], w1v = sw1[igw + 1];
        float mx = fmaxf(w0, w1v);
        float lse = mx + __logf(__expf(w0 - mx) + __expf(w1v - mx));
        float wm = (m == 0) ? w0 : w1v;
        int igs = ((o * 16 + p) * 2 + m) * 2;
        c0_l[il] = (wm - lse) - __logf(std1[igs]) - __logf(std1[igs + 1]) - LOG2PI_F;
    }
    for (int il = t; il < 512; il += 256) sc_l[il] = scopes1[il];
    if (t < 32) b1_l[t] = b1[t];

    const int wid  = t >> 6;          // wave 0..3 -> 16-row tile
    const int lane = t & 63;
    const int row0 = blockIdx.x * K1_ROWS;

    f32x4 acc0 = {0.f, 0.f, 0.f, 0.f};
    f32x4 acc1 = {0.f, 0.f, 0.f, 0.f};

    // ---- staged K loop: chunks of 64, reg-prefetch next chunk under MFMA ----
    float4 xr[4];
    #pragma unroll
    for (int i = 0; i < 4; ++i) {                 // chunk 0 (fully valid)
        int idx = i * 256 + t;
        int rr = idx >> 4, kq = idx & 15;
        xr[i] = *(const float4*)(x + (size_t)(row0 + rr) * 784 + kq * 4);
    }

    for (int c = 0; c < 13; ++c) {
        __syncthreads();                          // prev chunk consumed (and tables ready at c=0)
        // cvt + write current chunk (hi/lo)
        #pragma unroll
        for (int i = 0; i < 4; ++i) {
            int idx = i * 256 + t;
            int rr = idx >> 4, kq = idx & 15;
            float4 v = xr[i];
            float vv[4] = {v.x, v.y, v.z, v.w};
            #pragma unroll
            for (int e = 0; e < 4; ++e) {
                __hip_bfloat16 h = __float2bfloat16(vv[e]);
                float hf = __bfloat162float(h);
                Ah[rr][kq * 4 + e] = h;
                Al[rr][kq * 4 + e] = __float2bfloat16(vv[e] - hf);
            }
        }
        __syncthreads();
        // prefetch chunk c+1 (zero-fill past K=784)
        if (c < 12) {
            int kbase = (c + 1) * 64;
            #pragma unroll
            for (int i = 0; i < 4; ++i) {
                int idx = i * 256 + t;
                int rr = idx >> 4, kq = idx & 15;
                int kg = kbase + kq * 4;
                if (kg < 784)
                    xr[i] = *(const float4*)(x + (size_t)(row0 + rr) * 784 + kg);
                else
                    xr[i] = make_float4(0.f, 0.f, 0.f, 0.f);
            }
        }
        // compute: k32 steps (skip the all-zero step of the tail chunk)
        int nsteps = (c == 12) ? 1 : 2;
        for (int s = 0; s < nsteps; ++s) {
            int kloc = s * 32 + ((lane >> 4) & 3) * 8;
            int arow = wid * 16 + (lane & 15);
            bf16x8 ah = *(const bf16x8*)(&Ah[arow][kloc]);
            bf16x8 al = *(const bf16x8*)(&Al[arow][kloc]);
            int kb = c * 64 + kloc;
            int o0 = lane & 15;
            bf16x8 wh0 = *(const bf16x8*)(&w1h[o0 * WS1 + kb]);
            bf16x8 wl0 = *(const bf16x8*)(&w1l[o0 * WS1 + kb]);
            bf16x8 wh1 = *(const bf16x8*)(&w1h[(16 + o0) * WS1 + kb]);
            bf16x8 wl1 = *(const bf16x8*)(&w1l[(16 + o0) * WS1 + kb]);
            acc0 = __builtin_amdgcn_mfma_f32_16x16x32_bf16(ah, wh0, acc0, 0, 0, 0);
            acc0 = __builtin_amdgcn_mfma_f32_16x16x32_bf16(al, wh0, acc0, 0, 0, 0);
            acc0 = __builtin_amdgcn_mfma_f32_16x16x32_bf16(ah, wl0, acc0, 0, 0, 0);
            acc1 = __builtin_amdgcn_mfma_f32_16x16x32_bf16(ah, wh1, acc1, 0, 0, 0);
            acc1 = __builtin_amdgcn_mfma_f32_16x16x32_bf16(al, wh1, acc1, 0, 0, 0);
            acc1 = __builtin_amdgcn_mfma_f32_16x16x32_bf16(ah, wl1, acc1, 0, 0, 0);
        }
    }

    // ---- epilogue: bias + ReLU -> h_lds ----
    {
        int col = lane & 15;
        int rbase = wid * 16 + ((lane >> 4) & 3) * 4;
        #pragma unroll
        for (int r = 0; r < 4; ++r) {
            h_lds[rbase + r][col]      = fmaxf(acc0[r] + b1_l[col], 0.f);
            h_lds[rbase + r][16 + col] = fmaxf(acc1[r] + b1_l[16 + col], 0.f);
        }
    }
    __syncthreads();

    // ---- SPN1: 1024 (row, o) tasks over 256 threads ----
    for (int task = t; task < 1024; task += 256) {
        int row_l = task >> 4, o = task & 15;
        float outv = 0.f;
        for (int p = 0; p < 16; ++p) {
            int f0 = sc_l[o * 32 + 2 * p], f1 = sc_l[o * 32 + 2 * p + 1];
            float x0 = h_lds[row_l][f0];
            float x1 = h_lds[row_l][f1];
            float vm[2];
            #pragma unroll
            for (int m = 0; m < 2; ++m) {
                int base = ((p * 2 + m) * 2) * 16 + o;
                float d0 = (x0 - mu_l[base])      * inv_l[base];
                float d1 = (x1 - mu_l[base + 16]) * inv_l[base + 16];
                vm[m] = c0_l[(p * 2 + m) * 16 + o] - 0.5f * (d0 * d0 + d1 * d1);
            }
            float a  = fmaxf(vm[0], vm[1]);
            float bm = fminf(vm[0], vm[1]);
            outv += a + __logf(1.f + __expf(bm - a));
        }
        s1[(size_t)(row0 + row_l) * 16 + o] = outv;
        sv_l[o][row_l] = outv;
    }
    __syncthreads();

    // ---- per-block centered stats (sum, M2) per output column ----
    if (t < 16) {
        float s = 0.f;
        for (int rr = 0; rr < K1_ROWS; ++rr) s += sv_l[t][rr];
        float mb = s * (1.f / K1_ROWS);
        float m2 = 0.f;
        for (int rr = 0; rr < K1_ROWS; ++rr) { float d = sv_l[t][rr] - mb; m2 += d * d; }
        partials1[blockIdx.x * 32 + t]      = s;
        partials1[blockIdx.x * 32 + 16 + t] = m2;
    }
}

// ---------------- K2/K4: merge per-block stats -> {g, shift} ----------------
template <int NO, int NBLK, int RPB>
__global__ __launch_bounds__(256) void kreduce(
    const float* __restrict__ partials,
    const float* __restrict__ bn_w, const float* __restrict__ bn_b,
    float* __restrict__ stats)
{
    __shared__ double dsum[256];
    __shared__ double dmean[16];
    const int t = threadIdx.x;
    const int o = t & 15, seg = t >> 4;          // 16 segments
    const int per = NBLK / 16;

    double s = 0.0;
    if (o < NO)
        for (int b = seg * per; b < (seg + 1) * per; ++b)
            s += (double)partials[b * (2 * NO) + o];
    dsum[t] = s;
    __syncthreads();
    if (t < 16) {
        double S = 0.0;
        for (int g = 0; g < 16; ++g) S += dsum[g * 16 + t];
        dmean[t] = S / (double)BATCH;
    }
    __syncthreads();
    double mean = dmean[o];
    double m2 = 0.0;
    if (o < NO) {
        for (int b = seg * per; b < (seg + 1) * per; ++b) {
            double bm = (double)partials[b * (2 * NO) + o] / (double)RPB;
            double d  = bm - mean;
            m2 += (double)partials[b * (2 * NO) + NO + o] + (double)RPB * d * d;
        }
    }
    __syncthreads();
    dsum[t] = m2;
    __syncthreads();
    if (t < NO) {
        double M2 = 0.0;
        for (int g = 0; g < 16; ++g) M2 += dsum[g * 16 + t];
        double var = M2 / (double)BATCH;
        double gsc = (double)bn_w[t] / sqrt(var + (double)BN_EPS);
        stats[t]      = (float)gsc;
        stats[NO + t] = (float)((double)bn_b[t] - dmean[t] * gsc);
    }
}

// ---------------- K3: BN1 + SPN layer 2 ----------------
// block 320 threads = 32 rows x 10 outputs; grid 1024
__global__ __launch_bounds__(320, 4) void k3_spn2(
    const float* __restrict__ s1,
    const float* __restrict__ mean2, const float* __restrict__ std2, const float* __restrict__ sw2,
    const int* __restrict__ scopes2, const float* __restrict__ stats1,
    float* __restrict__ s2, float* __restrict__ partials2)
{
    __shared__ float mu_l[320], inv_l[320], c0_l[160];
    __shared__ int   sc_l[160];
    __shared__ float sv_l[10 * 33];
    __shared__ float g_l[16], sh_l[16];

    const int t = threadIdx.x;

    if (t < 320) {   // o-last: il = ((p*2+m)*2+f)*10 + o
        int o = t % 10, rest = t / 10;
        int f = rest & 1, m = (rest >> 1) & 1, p = rest >> 2;
        int ig = ((o * 8 + p) * 2 + m) * 2 + f;
        mu_l[t]  = mean2[ig];
        inv_l[t] = 1.0f / std2[ig];
    }
    if (t < 160) {   // il = (p*2+m)*10 + o
        int o = t % 10, rest = t / 10;
        int m = rest & 1, p = rest >> 1;
        int igw = (o * 8 + p) * 2;
        float w0 = sw2[igw], w1 = sw2[igw + 1];
        float mx = fmaxf(w0, w1);
        float lse = mx + __logf(__expf(w0 - mx) + __expf(w1 - mx));
        float wm = (m == 0) ? w0 : w1;
        int igs = ((o * 8 + p) * 2 + m) * 2;
        c0_l[t] = (wm - lse) - __logf(std2[igs]) - __logf(std2[igs + 1]) - LOG2PI_F;
    }
    if (t < 160) sc_l[t] = scopes2[t];
    if (t < 16)  g_l[t]  = stats1[t];
    else if (t < 32) sh_l[t - 16] = stats1[t];
    __syncthreads();

    const int row_l = t / 10, o = t % 10;
    const int row = blockIdx.x * RPB3 + row_l;
    const float* s1r = s1 + (size_t)row * 16;

    float v[16];
    #pragma unroll
    for (int f = 0; f < 16; ++f) v[f] = fmaf(s1r[f], g_l[f], sh_l[f]);

    float outv = 0.f;
    for (int p = 0; p < 8; ++p) {
        int f0 = sc_l[o * 16 + 2 * p], f1 = sc_l[o * 16 + 2 * p + 1];
        float x0 = v[f0], x1 = v[f1];
        float vm[2];
        #pragma unroll
        for (int m = 0; m < 2; ++m) {
            int base = ((p * 2 + m) * 2) * 10 + o;
            float d0 = (x0 - mu_l[base])      * inv_l[base];
            float d1 = (x1 - mu_l[base + 10]) * inv_l[base + 10];
            vm[m] = c0_l[(p * 2 + m) * 10 + o] - 0.5f * (d0 * d0 + d1 * d1);
        }
        float a  = fmaxf(vm[0], vm[1]);
        float bm = fminf(vm[0], vm[1]);
        outv += a + __logf(1.f + __expf(bm - a));
    }
    s2[(size_t)row * 10 + o] = outv;
    sv_l[o * 33 + row_l] = outv;
    __syncthreads();

    if (t < 10) {
        float s = 0.f;
        for (int rr = 0; rr < RPB3; ++rr) s += sv_l[t * 33 + rr];
        float mb = s * (1.f / RPB3);
        float m2 = 0.f;
        for (int rr = 0; rr < RPB3; ++rr) { float d = sv_l[t * 33 + rr] - mb; m2 += d * d; }
        partials2[blockIdx.x * 20 + t]      = s;
        partials2[blockIdx.x * 20 + 10 + t] = m2;
    }
}

// ---------------- K5: BN2 + final linear + log_softmax ----------------
__global__ __launch_bounds__(256) void k5_head(
    const float* __restrict__ s2, const float* __restrict__ stats2,
    const float* __restrict__ W2, const float* __restrict__ b2,
    float* __restrict__ out)
{
    const int row = blockIdx.x * 256 + threadIdx.x;
    const float* sr = s2 + (size_t)row * 10;
    float v[10], l[10];
    #pragma unroll
    for (int o = 0; o < 10; ++o) v[o] = fmaf(sr[o], stats2[o], stats2[10 + o]);
    float mx = -1e30f;
    #pragma unroll
    for (int c = 0; c < 10; ++c) {
        float a = b2[c];
        #pragma unroll
        for (int o = 0; o < 10; ++o) a = fmaf(W2[c * 10 + o], v[o], a);
        l[c] = a;
        mx = fmaxf(mx, a);
    }
    float sum = 0.f;
    #pragma unroll
    for (int c = 0; c < 10; ++c) sum += __expf(l[c] - mx);
    float ls = mx + __logf(sum);
    float* orow = out + (size_t)row * 10;
    #pragma unroll
    for (int c = 0; c < 10; ++c) orow[c] = l[c] - ls;
}

extern "C" void kernel_launch(void* const* d_in, const int* in_sizes, int n_in,
                              void* d_out, int out_size, void* d_ws, size_t ws_size,
                              hipStream_t stream) {
    const float* x      = (const float*)d_in[0];
    const float* W1     = (const float*)d_in[1];
    const float* b1     = (const float*)d_in[2];
    const float* mean1  = (const float*)d_in[3];
    const float* std1   = (const float*)d_in[4];
    const float* sw1    = (const float*)d_in[5];
    const float* bn1_w  = (const float*)d_in[6];
    const float* bn1_b  = (const float*)d_in[7];
    const float* mean2  = (const float*)d_in[8];
    const float* std2   = (const float*)d_in[9];
    const float* sw2    = (const float*)d_in[10];
    const float* bn2_w  = (const float*)d_in[11];
    const float* bn2_b  = (const float*)d_in[12];
    const float* W2     = (const float*)d_in[13];
    const float* b2     = (const float*)d_in[14];
    const int*   sc1    = (const int*)d_in[15];
    const int*   sc2    = (const int*)d_in[16];
    float* out = (float*)d_out;

    // workspace layout
    __hip_bfloat16* w1h = (__hip_bfloat16*)d_ws;           // 32*840
    __hip_bfloat16* w1l = w1h + 32 * WS1;                  // 32*840
    float* fbase = (float*)(w1l + 32 * WS1);               // 107520 B offset, 16B-aligned
    float* s1  = fbase;                    // 32768*16
    float* s2  = s1 + 32768 * 16;          // 32768*10
    float* p1  = s2 + 32768 * 10;          // 512*32
    float* p2  = p1 + NB1 * 32;            // 1024*20
    float* st1 = p2 + NB3 * 20;            // 32
    float* st2 = st1 + 32;                 // 20

    hipLaunchKernelGGL(k0_cvt, dim3((32 * WS1 + 255) / 256), dim3(256), 0, stream,
                       W1, w1h, w1l);
    hipLaunchKernelGGL(k1_gemm_spn1, dim3(NB1), dim3(256), 0, stream,
                       x, w1h, w1l, b1, mean1, std1, sw1, sc1, s1, p1);
    hipLaunchKernelGGL((kreduce<16, NB1, K1_ROWS>), dim3(1), dim3(256), 0, stream, p1, bn1_w, bn1_b, st1);
    hipLaunchKernelGGL(k3_spn2, dim3(NB3), dim3(320), 0, stream,
                       s1, mean2, std2, sw2, sc2, st1, s2, p2);
    hipLaunchKernelGGL((kreduce<10, NB3, RPB3>), dim3(1), dim3(256), 0, stream, p2, bn2_w, bn2_b, st2);
    hipLaunchKernelGGL(k5_head, dim3(32768 / 256), dim3(256), 0, stream,
                       s2, st2, W2, b2, out);
}

// Round 11
// 236.263 us; speedup vs baseline: 1.4240x; 1.0005x over previous
//
#include <hip/hip_runtime.h>
#include <hip/hip_bf16.h>
#include <math.h>

#define LOG2PI_F 1.8378770664093453f
#define BN_EPS 1e-5f
#define BATCH 32768

#define K1_ROWS 64
#define NB1 (BATCH / K1_ROWS)    // 512 blocks
#define WS1 840                  // padded K stride for bf16 W1 (>= 832, mult of 8)
#define NB3 1024                 // blocks for K3 (32 rows each)
#define RPB3 32

typedef __attribute__((ext_vector_type(8))) short bf16x8;
typedef __attribute__((ext_vector_type(4))) float f32x4;

__device__ __forceinline__ short f2bf_s(float f) {
    union { __hip_bfloat16 b; short s; } u;
    u.b = __float2bfloat16(f);
    return u.s;
}
__device__ __forceinline__ float bfs_to_f(short s) {
    return __uint_as_float(((unsigned)(unsigned short)s) << 16);
}

// ---------------- K0: W1 fp32 -> bf16 hi/lo (padded, zero-filled) ----------------
__global__ __launch_bounds__(256) void k0_cvt(
    const float* __restrict__ W1, __hip_bfloat16* __restrict__ w1h,
    __hip_bfloat16* __restrict__ w1l)
{
    int i = blockIdx.x * 256 + threadIdx.x;      // over 32*840 = 26880
    if (i >= 32 * WS1) return;
    int o = i / WS1, k = i - o * WS1;
    float w = (k < 784) ? W1[o * 784 + k] : 0.f;
    __hip_bfloat16 h = __float2bfloat16(w);
    float hf = __bfloat162float(h);
    __hip_bfloat16 l = __float2bfloat16(w - hf);
    w1h[i] = h;
    w1l[i] = l;
}

// ---------------- K1: x@W1.T + b1, ReLU, SPN layer 1 (MFMA bf16x3, no-LDS GEMM) ----
struct Step { float4 a0, a1; bf16x8 wh0, wl0, wh1, wl1; };

__device__ __forceinline__ void load_step(
    Step& S, const float* __restrict__ xrow,
    const __hip_bfloat16* __restrict__ wh, const __hip_bfloat16* __restrict__ wl,
    int s, int kgrp, int o0)
{
    int kb = s * 32 + kgrp * 8;
    int kc = (kb < 784) ? kb : 0;       // clamp addr; W zero-pad kills contribution
    S.a0 = *(const float4*)(xrow + kc);
    S.a1 = *(const float4*)(xrow + kc + 4);
    const __hip_bfloat16* ph = wh + o0 * WS1 + kb;
    const __hip_bfloat16* pl = wl + o0 * WS1 + kb;
    S.wh0 = *(const bf16x8*)(ph);
    S.wh1 = *(const bf16x8*)(ph + 16 * WS1);
    S.wl0 = *(const bf16x8*)(pl);
    S.wl1 = *(const bf16x8*)(pl + 16 * WS1);
}

__device__ __forceinline__ void comp_step(const Step& S, f32x4& acc0, f32x4& acc1)
{
    float av[8] = {S.a0.x, S.a0.y, S.a0.z, S.a0.w, S.a1.x, S.a1.y, S.a1.z, S.a1.w};
    bf16x8 ah, al;
    #pragma unroll
    for (int e = 0; e < 8; ++e) {
        float f = av[e];
        short h = f2bf_s(f);
        ah[e] = h;
        al[e] = f2bf_s(f - bfs_to_f(h));
    }
    acc0 = __builtin_amdgcn_mfma_f32_16x16x32_bf16(ah, S.wh0, acc0, 0, 0, 0);
    acc0 = __builtin_amdgcn_mfma_f32_16x16x32_bf16(al, S.wh0, acc0, 0, 0, 0);
    acc0 = __builtin_amdgcn_mfma_f32_16x16x32_bf16(ah, S.wl0, acc0, 0, 0, 0);
    acc1 = __builtin_amdgcn_mfma_f32_16x16x32_bf16(ah, S.wh1, acc1, 0, 0, 0);
    acc1 = __builtin_amdgcn_mfma_f32_16x16x32_bf16(al, S.wh1, acc1, 0, 0, 0);
    acc1 = __builtin_amdgcn_mfma_f32_16x16x32_bf16(ah, S.wl1, acc1, 0, 0, 0);
}

// block 256 threads = 4 waves x 16 rows; grid 512
__global__ __launch_bounds__(256, 2) void k1_gemm_spn1(
    const float* __restrict__ x,
    const __hip_bfloat16* __restrict__ w1h, const __hip_bfloat16* __restrict__ w1l,
    const float* __restrict__ b1,
    const float* __restrict__ mean1, const float* __restrict__ std1, const float* __restrict__ sw1,
    const int* __restrict__ scopes1,
    float* __restrict__ s1, float* __restrict__ partials1)
{
    __shared__ float h_lds[64][33];
    __shared__ float mu_l[1024], inv_l[1024], c0_l[512];
    __shared__ int   sc_l[512];
    __shared__ float b1_l[32];
    __shared__ float sv_l[16][66];

    const int t = threadIdx.x;

    // ---- SPN1 constant tables (LDS writes; no barrier needed until post-GEMM) ----
    for (int il = t; il < 1024; il += 256) {
        int o = il & 15, rest = il >> 4;
        int f = rest & 1, m = (rest >> 1) & 1, p = rest >> 2;
        int ig = ((o * 16 + p) * 2 + m) * 2 + f;
        mu_l[il]  = mean1[ig];
        inv_l[il] = 1.0f / std1[ig];
    }
    for (int il = t; il < 512; il += 256) {
        int o = il & 15, rest = il >> 4;
        int m = rest & 1, p = rest >> 1;
        int igw = (o * 16 + p) * 2;
        float w0 = sw1[igw], w1v = sw1[igw + 1];
        float mx = fmaxf(w0, w1v);
        float lse = mx + __logf(__expf(w0 - mx) + __expf(w1v - mx));
        float wm = (m == 0) ? w0 : w1v;
        int igs = ((o * 16 + p) * 2 + m) * 2;
        c0_l[il] = (wm - lse) - __logf(std1[igs]) - __logf(std1[igs + 1]) - LOG2PI_F;
    }
    for (int il = t; il < 512; il += 256) sc_l[il] = scopes1[il];
    if (t < 32) b1_l[t] = b1[t];

    const int wid  = t >> 6;
    const int lane = t & 63;
    const int row0 = blockIdx.x * K1_ROWS;
    const int kgrp = (lane >> 4) & 3;
    const int o0   = lane & 15;
    const float* xrow = x + (size_t)(row0 + wid * 16 + (lane & 15)) * 784;

    f32x4 acc0 = {0.f, 0.f, 0.f, 0.f};
    f32x4 acc1 = {0.f, 0.f, 0.f, 0.f};

    // ---- register-pipelined K loop: 24 steps as 8 groups of 3, ping-pong ----
    Step A0, A1, A2, B0, B1, B2;
    load_step(A0, xrow, w1h, w1l, 0, kgrp, o0);
    load_step(A1, xrow, w1h, w1l, 1, kgrp, o0);
    load_step(A2, xrow, w1h, w1l, 2, kgrp, o0);
    #pragma unroll
    for (int gg = 0; gg < 4; ++gg) {
        int g0 = gg * 6;
        load_step(B0, xrow, w1h, w1l, g0 + 3, kgrp, o0);
        load_step(B1, xrow, w1h, w1l, g0 + 4, kgrp, o0);
        load_step(B2, xrow, w1h, w1l, g0 + 5, kgrp, o0);
        comp_step(A0, acc0, acc1);
        comp_step(A1, acc0, acc1);
        comp_step(A2, acc0, acc1);
        if (gg < 3) {
            load_step(A0, xrow, w1h, w1l, g0 + 6, kgrp, o0);
            load_step(A1, xrow, w1h, w1l, g0 + 7, kgrp, o0);
            load_step(A2, xrow, w1h, w1l, g0 + 8, kgrp, o0);
        }
        comp_step(B0, acc0, acc1);
        comp_step(B1, acc0, acc1);
        comp_step(B2, acc0, acc1);
    }
    {   // tail step 24 (k 768..799; kgrp>=2 clamped, W pad = 0)
        Step T;
        load_step(T, xrow, w1h, w1l, 24, kgrp, o0);
        comp_step(T, acc0, acc1);
    }

    __syncthreads();   // tables + b1_l visible

    // ---- epilogue: bias + ReLU -> h_lds ----
    {
        int col = lane & 15;
        int rbase = wid * 16 + ((lane >> 4) & 3) * 4;
        #pragma unroll
        for (int r = 0; r < 4; ++r) {
            h_lds[rbase + r][col]      = fmaxf(acc0[r] + b1_l[col], 0.f);
            h_lds[rbase + r][16 + col] = fmaxf(acc1[r] + b1_l[16 + col], 0.f);
        }
    }
    __syncthreads();

    // ---- SPN1: 1024 (row, o) tasks over 256 threads ----
    for (int task = t; task < 1024; task += 256) {
        int row_l = task >> 4, o = task & 15;
        float outv = 0.f;
        for (int p = 0; p < 16; ++p) {
            int f0 = sc_l[o * 32 + 2 * p], f1 = sc_l[o * 32 + 2 * p + 1];
            float x0 = h_lds[row_l][f0];
            float x1 = h_lds[row_l][f1];
            float vm[2];
            #pragma unroll
            for (int m = 0; m < 2; ++m) {
                int base = ((p * 2 + m) * 2) * 16 + o;
                float d0 = (x0 - mu_l[base])      * inv_l[base];
                float d1 = (x1 - mu_l[base + 16]) * inv_l[base + 16];
                vm[m] = c0_l[(p * 2 + m) * 16 + o] - 0.5f * (d0 * d0 + d1 * d1);
            }
            float a  = fmaxf(vm[0], vm[1]);
            float bm = fminf(vm[0], vm[1]);
            outv += a + __logf(1.f + __expf(bm - a));
        }
        s1[(size_t)(row0 + row_l) * 16 + o] = outv;
        sv_l[o][row_l] = outv;
    }
    __syncthreads();

    // ---- per-block centered stats (sum, M2) per output column ----
    if (t < 16) {
        float s = 0.f;
        for (int rr = 0; rr < K1_ROWS; ++rr) s += sv_l[t][rr];
        float mb = s * (1.f / K1_ROWS);
        float m2 = 0.f;
        for (int rr = 0; rr < K1_ROWS; ++rr) { float d = sv_l[t][rr] - mb; m2 += d * d; }
        partials1[blockIdx.x * 32 + t]      = s;
        partials1[blockIdx.x * 32 + 16 + t] = m2;
    }
}

// ---------------- K2/K4: merge per-block stats -> {g, shift} ----------------
template <int NO, int NBLK, int RPB>
__global__ __launch_bounds__(256) void kreduce(
    const float* __restrict__ partials,
    const float* __restrict__ bn_w, const float* __restrict__ bn_b,
    float* __restrict__ stats)
{
    __shared__ double dsum[256];
    __shared__ double dmean[16];
    const int t = threadIdx.x;
    const int o = t & 15, seg = t >> 4;          // 16 segments
    const int per = NBLK / 16;

    double s = 0.0;
    if (o < NO)
        for (int b = seg * per; b < (seg + 1) * per; ++b)
            s += (double)partials[b * (2 * NO) + o];
    dsum[t] = s;
    __syncthreads();
    if (t < 16) {
        double S = 0.0;
        for (int g = 0; g < 16; ++g) S += dsum[g * 16 + t];
        dmean[t] = S / (double)BATCH;
    }
    __syncthreads();
    double mean = dmean[o];
    double m2 = 0.0;
    if (o < NO) {
        for (int b = seg * per; b < (seg + 1) * per; ++b) {
            double bm = (double)partials[b * (2 * NO) + o] / (double)RPB;
            double d  = bm - mean;
            m2 += (double)partials[b * (2 * NO) + NO + o] + (double)RPB * d * d;
        }
    }
    __syncthreads();
    dsum[t] = m2;
    __syncthreads();
    if (t < NO) {
        double M2 = 0.0;
        for (int g = 0; g < 16; ++g) M2 += dsum[g * 16 + t];
        double var = M2 / (double)BATCH;
        double gsc = (double)bn_w[t] / sqrt(var + (double)BN_EPS);
        stats[t]      = (float)gsc;
        stats[NO + t] = (float)((double)bn_b[t] - dmean[t] * gsc);
    }
}

// ---------------- K3: BN1 + SPN layer 2 (v staged in LDS — no scratch) ----------
// block 320 threads = 32 rows x 10 outputs; grid 1024
__global__ __launch_bounds__(320, 4) void k3_spn2(
    const float* __restrict__ s1,
    const float* __restrict__ mean2, const float* __restrict__ std2, const float* __restrict__ sw2,
    const int* __restrict__ scopes2, const float* __restrict__ stats1,
    float* __restrict__ s2, float* __restrict__ partials2)
{
    __shared__ float mu_l[320], inv_l[320], c0_l[160];
    __shared__ int   sc_l[160];
    __shared__ float v_lds[32][17];
    __shared__ float sv_l[10][33];
    __shared__ float g_l[16], sh_l[16];

    const int t = threadIdx.x;
    const int row0 = blockIdx.x * RPB3;

    if (t < 320) {   // o-last: il = ((p*2+m)*2+f)*10 + o
        int o = t % 10, rest = t / 10;
        int f = rest & 1, m = (rest >> 1) & 1, p = rest >> 2;
        int ig = ((o * 8 + p) * 2 + m) * 2 + f;
        mu_l[t]  = mean2[ig];
        inv_l[t] = 1.0f / std2[ig];
    }
    if (t < 160) {   // il = (p*2+m)*10 + o
        int o = t % 10, rest = t / 10;
        int m = rest & 1, p = rest >> 1;
        int igw = (o * 8 + p) * 2;
        float w0 = sw2[igw], w1 = sw2[igw + 1];
        float mx = fmaxf(w0, w1);
        float lse = mx + __logf(__expf(w0 - mx) + __expf(w1 - mx));
        float wm = (m == 0) ? w0 : w1;
        int igs = ((o * 8 + p) * 2 + m) * 2;
        c0_l[t] = (wm - lse) - __logf(std2[igs]) - __logf(std2[igs + 1]) - LOG2PI_F;
    }
    if (t < 160) sc_l[t] = scopes2[t];
    if (t < 16)  g_l[t]  = stats1[t];
    else if (t >= 64 && t < 80) sh_l[t - 64] = stats1[16 + (t - 64)];
    __syncthreads();

    // stage BN'd rows: 512 coalesced loads
    for (int i = t; i < 512; i += 320) {
        int rl = i >> 4, f = i & 15;
        v_lds[rl][f] = fmaf(s1[(size_t)(row0 + rl) * 16 + f], g_l[f], sh_l[f]);
    }
    __syncthreads();

    const int row_l = t / 10, o = t % 10;
    float outv = 0.f;
    for (int p = 0; p < 8; ++p) {
        int f0 = sc_l[o * 16 + 2 * p], f1 = sc_l[o * 16 + 2 * p + 1];
        float x0 = v_lds[row_l][f0], x1 = v_lds[row_l][f1];
        float vm[2];
        #pragma unroll
        for (int m = 0; m < 2; ++m) {
            int base = ((p * 2 + m) * 2) * 10 + o;
            float d0 = (x0 - mu_l[base])      * inv_l[base];
            float d1 = (x1 - mu_l[base + 10]) * inv_l[base + 10];
            vm[m] = c0_l[(p * 2 + m) * 10 + o] - 0.5f * (d0 * d0 + d1 * d1);
        }
        float a  = fmaxf(vm[0], vm[1]);
        float bm = fminf(vm[0], vm[1]);
        outv += a + __logf(1.f + __expf(bm - a));
    }
    s2[(size_t)(row0 + row_l) * 10 + o] = outv;
    sv_l[o][row_l] = outv;
    __syncthreads();

    if (t < 10) {
        float s = 0.f;
        for (int rr = 0; rr < RPB3; ++rr) s += sv_l[t][rr];
        float mb = s * (1.f / RPB3);
        float m2 = 0.f;
        for (int rr = 0; rr < RPB3; ++rr) { float d = sv_l[t][rr] - mb; m2 += d * d; }
        partials2[blockIdx.x * 20 + t]      = s;
        partials2[blockIdx.x * 20 + 10 + t] = m2;
    }
}

// ---------------- K5: BN2 + final linear + log_softmax ----------------
// 128 threads x 256 blocks
__global__ __launch_bounds__(128) void k5_head(
    const float* __restrict__ s2, const float* __restrict__ stats2,
    const float* __restrict__ W2, const float* __restrict__ b2,
    float* __restrict__ out)
{
    __shared__ float w2_l[100], b2_l[10], st_l[20];
    const int t = threadIdx.x;
    if (t < 100) w2_l[t] = W2[t];
    if (t < 10)  b2_l[t] = b2[t];
    if (t < 20)  st_l[t] = stats2[t];
    __syncthreads();

    const int row = blockIdx.x * 128 + t;
    const float* sr = s2 + (size_t)row * 10;
    float v[10], l[10];
    #pragma unroll
    for (int i = 0; i < 5; ++i) {
        float2 p = *(const float2*)(sr + 2 * i);
        v[2*i]   = fmaf(p.x, st_l[2*i],   st_l[10 + 2*i]);
        v[2*i+1] = fmaf(p.y, st_l[2*i+1], st_l[10 + 2*i+1]);
    }
    float mx = -1e30f;
    #pragma unroll
    for (int c = 0; c < 10; ++c) {
        float a = b2_l[c];
        #pragma unroll
        for (int o = 0; o < 10; ++o) a = fmaf(w2_l[c * 10 + o], v[o], a);
        l[c] = a;
        mx = fmaxf(mx, a);
    }
    float sum = 0.f;
    #pragma unroll
    for (int c = 0; c < 10; ++c) sum += __expf(l[c] - mx);
    float ls = mx + __logf(sum);
    float* orow = out + (size_t)row * 10;
    #pragma unroll
    for (int c = 0; c < 10; ++c) orow[c] = l[c] - ls;
}

extern "C" void kernel_launch(void* const* d_in, const int* in_sizes, int n_in,
                              void* d_out, int out_size, void* d_ws, size_t ws_size,
                              hipStream_t stream) {
    const float* x      = (const float*)d_in[0];
    const float* W1     = (const float*)d_in[1];
    const float* b1     = (const float*)d_in[2];
    const float* mean1  = (const float*)d_in[3];
    const float* std1   = (const float*)d_in[4];
    const float* sw1    = (const float*)d_in[5];
    const float* bn1_w  = (const float*)d_in[6];
    const float* bn1_b  = (const float*)d_in[7];
    const float* mean2  = (const float*)d_in[8];
    const float* std2   = (const float*)d_in[9];
    const float* sw2    = (const float*)d_in[10];
    const float* bn2_w  = (const float*)d_in[11];
    const float* bn2_b  = (const float*)d_in[12];
    const float* W2     = (const float*)d_in[13];
    const float* b2     = (const float*)d_in[14];
    const int*   sc1    = (const int*)d_in[15];
    const int*   sc2    = (const int*)d_in[16];
    float* out = (float*)d_out;

    // workspace layout
    __hip_bfloat16* w1h = (__hip_bfloat16*)d_ws;           // 32*840
    __hip_bfloat16* w1l = w1h + 32 * WS1;                  // 32*840
    float* fbase = (float*)(w1l + 32 * WS1);               // 16B-aligned
    float* s1  = fbase;                    // 32768*16
    float* s2  = s1 + 32768 * 16;          // 32768*10
    float* p1  = s2 + 32768 * 10;          // 512*32
    float* p2  = p1 + NB1 * 32;            // 1024*20
    float* st1 = p2 + NB3 * 20;            // 32
    float* st2 = st1 + 32;                 // 20

    hipLaunchKernelGGL(k0_cvt, dim3((32 * WS1 + 255) / 256), dim3(256), 0, stream,
                       W1, w1h, w1l);
    hipLaunchKernelGGL(k1_gemm_spn1, dim3(NB1), dim3(256), 0, stream,
                       x, w1h, w1l, b1, mean1, std1, sw1, sc1, s1, p1);
    hipLaunchKernelGGL((kreduce<16, NB1, K1_ROWS>), dim3(1), dim3(256), 0, stream, p1, bn1_w, bn1_b, st1);
    hipLaunchKernelGGL(k3_spn2, dim3(NB3), dim3(320), 0, stream,
                       s1, mean2, std2, sw2, sc2, st1, s2, p2);
    hipLaunchKernelGGL((kreduce<10, NB3, RPB3>), dim3(1), dim3(256), 0, stream, p2, bn2_w, bn2_b, st2);
    hipLaunchKernelGGL(k5_head, dim3(BATCH / 128), dim3(128), 0, stream,
                       s2, st2, W2, b2, out);
}